// Round 1
// baseline (7167.621 us; speedup 1.0000x reference)
//
#include <hip/hip_runtime.h>
#include <hip/hip_bf16.h>

// Problem constants (from reference setup_inputs)
#define Bdim 64
#define Sdim 96
#define Hdim 1024
#define Edim 512
#define Vdim 32000
#define Tdim 32
// d_out layout: decoder_outputs [B,T,V] | h_T [1,B,H] | attentions [B,T,S]
#define O1 65536000L   // B*T*V
#define O2 65601536L   // + B*H
#define TV 1024000L    // T*V

typedef short short8 __attribute__((ext_vector_type(8)));   // 8 bf16 (4 VGPRs)
typedef float f32x4 __attribute__((ext_vector_type(4)));

__device__ __forceinline__ unsigned short f2bf(float f) {
  unsigned u = __builtin_bit_cast(unsigned, f);
  unsigned r = (u + 0x7fffu + ((u >> 16) & 1u)) >> 16;  // RTN-even
  return (unsigned short)r;
}

// ---------- one-time kernels ----------

// u[g] = sum_h Va[h] * Ua[h*H + g]   (scores fold: Va^T Ua)
__global__ void k_u(const float* __restrict__ Va, const float* __restrict__ Ua,
                    float* __restrict__ u) {
  int lane = threadIdx.x & 63, wv = threadIdx.x >> 6;
  int g = blockIdx.x * 64 + lane;
  float acc = 0.f;
  for (int h = wv * 256; h < wv * 256 + 256; ++h)
    acc = fmaf(Va[h], Ua[h * Hdim + g], acc);
  __shared__ float red[4][64];
  red[wv][lane] = acc;
  __syncthreads();
  if (threadIdx.x < 64)
    u[blockIdx.x * 64 + threadIdx.x] =
        red[0][threadIdx.x] + red[1][threadIdx.x] + red[2][threadIdx.x] + red[3][threadIdx.x];
}

// sc[b,s] = keys[b,s,:] . u   (one wave per (b,s))
__global__ void k_sc(const float* __restrict__ keys, const float* __restrict__ u,
                     float* __restrict__ sc) {
  int wid = blockIdx.x * 4 + (threadIdx.x >> 6);
  int lane = threadIdx.x & 63;
  int b = wid / Sdim, s = wid % Sdim;
  const float* kp = keys + ((long)b * Sdim + s) * Hdim;
  float acc = 0.f;
  #pragma unroll 4
  for (int g = lane; g < Hdim; g += 64) acc = fmaf(kp[g], u[g], acc);
  for (int off = 32; off; off >>= 1) acc += __shfl_down(acc, off);
  if (lane == 0) sc[wid] = acc;
}

// softmax over s, write attentions for all t (step-independent!), ctxT[h][b]
__global__ void k_softmax_ctx(const float* __restrict__ sc, const float* __restrict__ keys,
                              float* __restrict__ attn, float* __restrict__ ctxT) {
  int b = blockIdx.x, tid = threadIdx.x;  // 128 threads
  __shared__ float w[Sdim];
  __shared__ float mx, sm;
  if (tid == 0) {
    float m = -1e30f;
    for (int s = 0; s < Sdim; ++s) m = fmaxf(m, sc[b * Sdim + s]);
    mx = m;
  }
  __syncthreads();
  if (tid < Sdim) w[tid] = expf(sc[b * Sdim + tid] - mx);
  __syncthreads();
  if (tid == 0) {
    float s = 0.f;
    for (int i = 0; i < Sdim; ++i) s += w[i];
    sm = s;
  }
  __syncthreads();
  if (tid < Sdim) w[tid] = w[tid] / sm;
  __syncthreads();
  for (int i = tid; i < Tdim * Sdim; i += 128)
    attn[(long)b * (Tdim * Sdim) + i] = w[i % Sdim];
  for (int h = tid; h < Hdim; h += 128) {
    float acc = 0.f;
    for (int s = 0; s < Sdim; ++s)
      acc = fmaf(w[s], keys[((long)b * Sdim + s) * Hdim + h], acc);
    ctxT[h * 64 + b] = acc;
  }
}

// gctxT[j][b] = b_ih[j] + sum_h ctxT[h][b] * W_ih[j, E+h]
__global__ void k_gctx(const float* __restrict__ ctxT, const float* __restrict__ Wih,
                       const float* __restrict__ bih, float* __restrict__ gctxT) {
  int j = __builtin_amdgcn_readfirstlane(blockIdx.x * 4 + (threadIdx.x >> 6));
  int lane = threadIdx.x & 63;
  const float* wp = Wih + (long)j * (Edim + Hdim) + Edim;
  float acc = 0.f;
  #pragma unroll 4
  for (int h = 0; h < Hdim; ++h) acc = fmaf(ctxT[h * 64 + lane], wp[h], acc);
  gctxT[j * 64 + lane] = acc + bih[j];
}

// hT[k][b] = h0[b][k]; embT[e][b] = relu(emb_table[START=1][e])
__global__ void k_init(const float* __restrict__ h0, const float* __restrict__ embt,
                       float* __restrict__ hT, float* __restrict__ embT) {
  int idx = blockIdx.x * 256 + threadIdx.x;
  if (idx < Bdim * Hdim) {
    int b = idx >> 10, k = idx & 1023;
    hT[k * 64 + b] = h0[idx];
  } else {
    int j = idx - Bdim * Hdim;
    if (j < Edim * 64) {
      int e = j >> 6;
      float x = embt[1 * Edim + e];
      embT[j] = x > 0.f ? x : 0.f;
    }
  }
}

// W_out fp32 -> bf16 copy (one time)
__global__ void k_w2b(const float* __restrict__ W, unsigned short* __restrict__ Wb) {
  long i = ((long)blockIdx.x * 256 + threadIdx.x) * 8;
  float4 a = *(const float4*)(W + i);
  float4 b = *(const float4*)(W + i + 4);
  short8 v;
  v[0] = (short)f2bf(a.x); v[1] = (short)f2bf(a.y); v[2] = (short)f2bf(a.z); v[3] = (short)f2bf(a.w);
  v[4] = (short)f2bf(b.x); v[5] = (short)f2bf(b.y); v[6] = (short)f2bf(b.z); v[7] = (short)f2bf(b.w);
  *(short8*)(Wb + i) = v;
}

// ---------- per-step kernels ----------

// GRU step, fp32. 4 hid per block, 8 K-slice waves. lane = b.
__launch_bounds__(512)
__global__ void k_gru(const float* __restrict__ hT_in, float* __restrict__ hT_out,
                      const float* __restrict__ embT, const float* __restrict__ gctxT,
                      const float* __restrict__ Wih, const float* __restrict__ Whh,
                      const float* __restrict__ bhh,
                      float* __restrict__ hrow, unsigned short* __restrict__ hb) {
  int tid = threadIdx.x, lane = tid & 63, wv = tid >> 6;  // wv 0..7
  int hid0 = blockIdx.x * 4;
  float accE[4][3], accH[4][3];
  #pragma unroll
  for (int hi = 0; hi < 4; ++hi)
    for (int q = 0; q < 3; ++q) { accE[hi][q] = 0.f; accH[hi][q] = 0.f; }

  #pragma unroll 2
  for (int e = wv * 64; e < wv * 64 + 64; ++e) {
    float v = embT[e * 64 + lane];
    #pragma unroll
    for (int hi = 0; hi < 4; ++hi) {
      int hid = hid0 + hi;
      accE[hi][0] = fmaf(v, Wih[(long)hid * 1536 + e], accE[hi][0]);
      accE[hi][1] = fmaf(v, Wih[(long)(Hdim + hid) * 1536 + e], accE[hi][1]);
      accE[hi][2] = fmaf(v, Wih[(long)(2 * Hdim + hid) * 1536 + e], accE[hi][2]);
    }
  }
  #pragma unroll 2
  for (int k = wv * 128; k < wv * 128 + 128; ++k) {
    float v = hT_in[k * 64 + lane];
    #pragma unroll
    for (int hi = 0; hi < 4; ++hi) {
      int hid = hid0 + hi;
      accH[hi][0] = fmaf(v, Whh[(long)hid * Hdim + k], accH[hi][0]);
      accH[hi][1] = fmaf(v, Whh[(long)(Hdim + hid) * Hdim + k], accH[hi][1]);
      accH[hi][2] = fmaf(v, Whh[(long)(2 * Hdim + hid) * Hdim + k], accH[hi][2]);
    }
  }
  __shared__ float red[4][6][8][64];  // 48 KB
  #pragma unroll
  for (int hi = 0; hi < 4; ++hi) {
    red[hi][0][wv][lane] = accE[hi][0]; red[hi][1][wv][lane] = accE[hi][1];
    red[hi][2][wv][lane] = accE[hi][2]; red[hi][3][wv][lane] = accH[hi][0];
    red[hi][4][wv][lane] = accH[hi][1]; red[hi][5][wv][lane] = accH[hi][2];
  }
  __syncthreads();
  if (tid < 256) {
    int hi = tid >> 6, b = tid & 63, hid = hid0 + hi;
    float s0 = 0, s1 = 0, s2 = 0, s3 = 0, s4 = 0, s5 = 0;
    #pragma unroll
    for (int w2 = 0; w2 < 8; ++w2) {
      s0 += red[hi][0][w2][b]; s1 += red[hi][1][w2][b]; s2 += red[hi][2][w2][b];
      s3 += red[hi][3][w2][b]; s4 += red[hi][4][w2][b]; s5 += red[hi][5][w2][b];
    }
    float gr = gctxT[hid * 64 + b] + s0;
    float gz = gctxT[(Hdim + hid) * 64 + b] + s1;
    float gn = gctxT[(2 * Hdim + hid) * 64 + b] + s2;
    float hr = s3 + bhh[hid];
    float hz = s4 + bhh[Hdim + hid];
    float hn = s5 + bhh[2 * Hdim + hid];
    float r = 1.f / (1.f + expf(-(gr + hr)));
    float z = 1.f / (1.f + expf(-(gz + hz)));
    float n = tanhf(gn + r * hn);
    float hold = hT_in[hid * 64 + b];
    float hnew = (1.f - z) * n + z * hold;
    hT_out[hid * 64 + b] = hnew;
    hrow[b * Hdim + hid] = hnew;            // also serves as h_T output slot
    hb[b * Hdim + hid] = f2bf(hnew);
  }
}

// logits[b,v] = h_bf16[b,:] . W_out_bf16[v,:] + b_out[v]  via MFMA 16x16x32 bf16
// Each wave: 16 cols (n) x 64 rows (b, 4 m-tiles). Also per-block per-b max -> wsmax.
template <int WB>
__launch_bounds__(256)
__global__ void k_logits(const unsigned short* __restrict__ hbv,
                         const unsigned short* __restrict__ Wb,
                         const float* __restrict__ Wf,
                         const float* __restrict__ bout, float* __restrict__ out,
                         int t, float* __restrict__ wsmax) {
  int tid = threadIdx.x, wv = tid >> 6, lane = tid & 63;
  int l15 = lane & 15, quad = lane >> 4;
  int n16 = (blockIdx.x * 4 + wv) * 16;
  int vcol = n16 + l15;
  f32x4 acc[4];
  #pragma unroll
  for (int mt = 0; mt < 4; ++mt) acc[mt] = (f32x4){0.f, 0.f, 0.f, 0.f};
  const unsigned short* A = hbv + l15 * Hdim + quad * 8;
  const unsigned short* Bq = WB ? (Wb + (long)vcol * Hdim + quad * 8) : nullptr;
  const float* Bqf = WB ? nullptr : (Wf + (long)vcol * Hdim + quad * 8);
  #pragma unroll 4
  for (int ks = 0; ks < 32; ++ks) {
    int k0 = ks * 32;
    short8 bf;
    if (WB) {
      bf = *(const short8*)(Bq + k0);
    } else {
      float4 x = *(const float4*)(Bqf + k0);
      float4 y = *(const float4*)(Bqf + k0 + 4);
      bf[0] = (short)f2bf(x.x); bf[1] = (short)f2bf(x.y); bf[2] = (short)f2bf(x.z); bf[3] = (short)f2bf(x.w);
      bf[4] = (short)f2bf(y.x); bf[5] = (short)f2bf(y.y); bf[6] = (short)f2bf(y.z); bf[7] = (short)f2bf(y.w);
    }
    short8 a0 = *(const short8*)(A + k0);
    short8 a1 = *(const short8*)(A + 16 * Hdim + k0);
    short8 a2 = *(const short8*)(A + 32 * Hdim + k0);
    short8 a3 = *(const short8*)(A + 48 * Hdim + k0);
    acc[0] = __builtin_amdgcn_mfma_f32_16x16x32_bf16(a0, bf, acc[0], 0, 0, 0);
    acc[1] = __builtin_amdgcn_mfma_f32_16x16x32_bf16(a1, bf, acc[1], 0, 0, 0);
    acc[2] = __builtin_amdgcn_mfma_f32_16x16x32_bf16(a2, bf, acc[2], 0, 0, 0);
    acc[3] = __builtin_amdgcn_mfma_f32_16x16x32_bf16(a3, bf, acc[3], 0, 0, 0);
  }
  __shared__ float lmax[4][64];
  float bo = bout[vcol];
  #pragma unroll
  for (int mt = 0; mt < 4; ++mt) {
    #pragma unroll
    for (int r = 0; r < 4; ++r) {
      float val = acc[mt][r] + bo;
      int brow = mt * 16 + quad * 4 + r;  // C/D: row=quad*4+reg, col=l15 (m89-verified)
      out[(long)brow * TV + (long)t * Vdim + vcol] = val;
      float m = val;
      m = fmaxf(m, __shfl_xor(m, 1));
      m = fmaxf(m, __shfl_xor(m, 2));
      m = fmaxf(m, __shfl_xor(m, 4));
      m = fmaxf(m, __shfl_xor(m, 8));
      if (l15 == 0) lmax[wv][brow] = m;
    }
  }
  __syncthreads();
  if (tid < 64) {
    float m = fmaxf(fmaxf(lmax[0][tid], lmax[1][tid]), fmaxf(lmax[2][tid], lmax[3][tid]));
    wsmax[tid * 512 + blockIdx.x] = m;
  }
}

// greedy argmax with fp32 recheck of near-max candidates; gather next embedding
__global__ void k_argmax(const float* __restrict__ wsmax, const float* __restrict__ out,
                         const float* __restrict__ hrow, const float* __restrict__ Wout,
                         const float* __restrict__ bout, const float* __restrict__ embt,
                         float* __restrict__ embT, int t) {
  int b = blockIdx.x, tid = threadIdx.x;
  __shared__ float lred[4];
  __shared__ float thr_s;
  __shared__ int cnt, tok_s;
  __shared__ int cand[64];
  __shared__ float cval[64];
  float m = -1e30f;
  for (int i = tid; i < 500; i += 256) m = fmaxf(m, wsmax[b * 512 + i]);
  for (int off = 32; off; off >>= 1) m = fmaxf(m, __shfl_down(m, off));
  if ((tid & 63) == 0) lred[tid >> 6] = m;
  if (tid == 0) cnt = 0;
  __syncthreads();
  if (tid == 0)
    thr_s = fmaxf(fmaxf(lred[0], lred[1]), fmaxf(lred[2], lred[3])) - 0.03f;
  __syncthreads();
  const float* L = out + (long)b * TV + (long)t * Vdim;
  for (int v = tid; v < Vdim; v += 256) {
    float val = L[v];
    if (val >= thr_s) {
      int i = atomicAdd(&cnt, 1);
      if (i < 64) cand[i] = v;
    }
  }
  __syncthreads();
  int C = min(cnt, 64);
  for (int c = 0; c < C; ++c) {
    int v = cand[c];
    const float* wr = Wout + (long)v * Hdim;
    const float* hr = hrow + b * Hdim;
    float p = 0.f;
    for (int k = tid; k < Hdim; k += 256) p = fmaf(hr[k], wr[k], p);
    for (int off = 32; off; off >>= 1) p += __shfl_down(p, off);
    __syncthreads();  // protect lred reuse
    if ((tid & 63) == 0) lred[tid >> 6] = p;
    __syncthreads();
    if (tid == 0) cval[c] = lred[0] + lred[1] + lred[2] + lred[3] + bout[v];
  }
  __syncthreads();
  if (tid == 0) {
    float best = -1e30f;
    int bi = 0x7fffffff;
    for (int c = 0; c < C; ++c)
      if (cval[c] > best || (cval[c] == best && cand[c] < bi)) { best = cval[c]; bi = cand[c]; }
    tok_s = bi;
  }
  __syncthreads();
  int tok = tok_s;
  for (int e = tid; e < Edim; e += 256) {
    float x = embt[(long)tok * Edim + e];
    embT[e * 64 + b] = x > 0.f ? x : 0.f;
  }
}

// ---------- host ----------

extern "C" void kernel_launch(void* const* d_in, const int* in_sizes, int n_in,
                              void* d_out, int out_size, void* d_ws, size_t ws_size,
                              hipStream_t stream) {
  const float* keys = (const float*)d_in[0];
  const float* h0   = (const float*)d_in[1];
  const float* embt = (const float*)d_in[2];
  const float* Ua   = (const float*)d_in[4];
  const float* Va   = (const float*)d_in[5];
  const float* Wih  = (const float*)d_in[6];
  const float* Whh  = (const float*)d_in[7];
  const float* bih  = (const float*)d_in[8];
  const float* bhh  = (const float*)d_in[9];
  const float* Wout = (const float*)d_in[10];
  const float* bout = (const float*)d_in[11];
  float* out = (float*)d_out;

  char* ws = (char*)d_ws;
  float* u     = (float*)(ws + 0);
  float* sc    = (float*)(ws + 4096);
  float* ctxT  = (float*)(ws + 28672);
  float* gctxT = (float*)(ws + 290816);
  float* hTa   = (float*)(ws + 1077248);
  float* hTb   = (float*)(ws + 1339392);
  float* embT  = (float*)(ws + 1601536);
  float* wsmax = (float*)(ws + 1732608);
  unsigned short* hb = (unsigned short*)(ws + 1863680);
  unsigned short* Wb = (unsigned short*)(ws + 1994752);
  bool useBf = ws_size >= 67530752ull;  // room for bf16 W_out copy?

  float* houtrow = out + O1;  // h_T slot, overwritten each step (last wins)
  float* attn = out + O2;

  k_u<<<16, 256, 0, stream>>>(Va, Ua, u);
  k_sc<<<1536, 256, 0, stream>>>(keys, u, sc);
  k_softmax_ctx<<<64, 128, 0, stream>>>(sc, keys, attn, ctxT);
  k_gctx<<<768, 256, 0, stream>>>(ctxT, Wih, bih, gctxT);
  k_init<<<384, 256, 0, stream>>>(h0, embt, hTa, embT);
  if (useBf) k_w2b<<<16000, 256, 0, stream>>>(Wout, Wb);

  float* hin = hTa;
  float* hout = hTb;
  for (int t = 0; t < Tdim; ++t) {
    k_gru<<<256, 512, 0, stream>>>(hin, hout, embT, gctxT, Wih, Whh, bhh, houtrow, hb);
    if (useBf)
      k_logits<1><<<500, 256, 0, stream>>>(hb, Wb, nullptr, bout, out, t, wsmax);
    else
      k_logits<0><<<500, 256, 0, stream>>>(hb, nullptr, Wout, bout, out, t, wsmax);
    if (t < Tdim - 1)
      k_argmax<<<64, 256, 0, stream>>>(wsmax, out, houtrow, Wout, bout, embt, embT, t);
    float* tmp = hin; hin = hout; hout = tmp;
  }
}

// Round 2
// 3676.053 us; speedup vs baseline: 1.9498x; 1.9498x over previous
//
#include <hip/hip_runtime.h>
#include <hip/hip_bf16.h>

// Problem constants (from reference setup_inputs)
#define Bdim 64
#define Sdim 96
#define Hdim 1024
#define Edim 512
#define Vdim 32000
#define Tdim 32
// d_out layout: decoder_outputs [B,T,V] | h_T [1,B,H] | attentions [B,T,S]
#define O1 65536000L   // B*T*V
#define O2 65601536L   // + B*H
#define TV 1024000L    // T*V

typedef short short8 __attribute__((ext_vector_type(8)));   // 8 bf16 (4 VGPRs)
typedef float f32x4 __attribute__((ext_vector_type(4)));

__device__ __forceinline__ unsigned short f2bf(float f) {
  unsigned u = __builtin_bit_cast(unsigned, f);
  unsigned r = (u + 0x7fffu + ((u >> 16) & 1u)) >> 16;  // RTN-even
  return (unsigned short)r;
}

// ---------- one-time kernels ----------

// phase 1: pu[hc][g] = sum over 128 h of Va[h]*Ua[h][g]   (grid 16 gc x 8 hc)
__global__ void k_u1(const float* __restrict__ Va, const float* __restrict__ Ua,
                     float* __restrict__ pu) {
  int gc = blockIdx.x & 15, hc = blockIdx.x >> 4;
  int lane = threadIdx.x & 63, wv = threadIdx.x >> 6;
  int g = gc * 64 + lane;
  int h0 = hc * 128 + wv * 32;
  float acc = 0.f;
  #pragma unroll 8
  for (int h = h0; h < h0 + 32; ++h) acc = fmaf(Va[h], Ua[(long)h * Hdim + g], acc);
  __shared__ float red[4][64];
  red[wv][lane] = acc;
  __syncthreads();
  if (threadIdx.x < 64)
    pu[hc * Hdim + gc * 64 + threadIdx.x] =
        red[0][threadIdx.x] + red[1][threadIdx.x] + red[2][threadIdx.x] + red[3][threadIdx.x];
}

__global__ void k_u2(const float* __restrict__ pu, float* __restrict__ u) {
  int g = blockIdx.x * 256 + threadIdx.x;
  float s = 0.f;
  #pragma unroll
  for (int i = 0; i < 8; ++i) s += pu[i * Hdim + g];
  u[g] = s;
}

// sc[b,s] = keys[b,s,:] . u   (one wave per (b,s))
__global__ void k_sc(const float* __restrict__ keys, const float* __restrict__ u,
                     float* __restrict__ sc) {
  int wid = blockIdx.x * 4 + (threadIdx.x >> 6);
  int lane = threadIdx.x & 63;
  int b = wid / Sdim, s = wid % Sdim;
  const float* kp = keys + ((long)b * Sdim + s) * Hdim;
  float acc = 0.f;
  #pragma unroll 4
  for (int g = lane; g < Hdim; g += 64) acc = fmaf(kp[g], u[g], acc);
  for (int off = 32; off; off >>= 1) acc += __shfl_down(acc, off);
  if (lane == 0) sc[wid] = acc;
}

// softmax over s (parallel), write w -> wbuf and broadcast attentions for all t
__global__ void k_softmax(const float* __restrict__ sc, float* __restrict__ wbuf,
                          float* __restrict__ attn) {
  int b = blockIdx.x, tid = threadIdx.x;  // 128 threads
  __shared__ float sv[128];
  __shared__ float sw[Sdim];
  float v = (tid < Sdim) ? sc[b * Sdim + tid] : -1e30f;
  sv[tid] = v;
  __syncthreads();
  for (int off = 64; off >= 1; off >>= 1) {
    if (tid < off) sv[tid] = fmaxf(sv[tid], sv[tid + off]);
    __syncthreads();
  }
  float mx = sv[0];
  __syncthreads();
  float e = (tid < Sdim) ? expf(v - mx) : 0.f;
  sv[tid] = e;
  __syncthreads();
  for (int off = 64; off >= 1; off >>= 1) {
    if (tid < off) sv[tid] += sv[tid + off];
    __syncthreads();
  }
  float sm = sv[0];
  if (tid < Sdim) {
    float w = e / sm;
    sw[tid] = w;
    wbuf[b * Sdim + tid] = w;
  }
  __syncthreads();
  for (int i = tid; i < Tdim * Sdim; i += 128)
    attn[(long)b * (Tdim * Sdim) + i] = sw[i % Sdim];
}

// ctxT[h][b] = sum_s w[b][s]*keys[b][s][h].  grid 64 b x 8 slabs, 256 thr.
__global__ void k_ctx(const float* __restrict__ wbuf, const float* __restrict__ keys,
                      float* __restrict__ ctxT) {
  int b = blockIdx.x >> 3, slab = blockIdx.x & 7;
  int tid = threadIdx.x;
  __shared__ float sw[Sdim];
  __shared__ float4 red[8][32];
  if (tid < Sdim) sw[tid] = wbuf[b * Sdim + tid];
  __syncthreads();
  int hq = tid & 31, sg = tid >> 5;  // 32 h-quads (128 h), 8 s-groups of 12
  const float* kp = keys + ((long)b * Sdim + sg * 12) * Hdim + slab * 128 + hq * 4;
  float4 acc = {0.f, 0.f, 0.f, 0.f};
  #pragma unroll
  for (int s = 0; s < 12; ++s) {
    float4 k4 = *(const float4*)(kp + (long)s * Hdim);
    float w = sw[sg * 12 + s];
    acc.x = fmaf(w, k4.x, acc.x); acc.y = fmaf(w, k4.y, acc.y);
    acc.z = fmaf(w, k4.z, acc.z); acc.w = fmaf(w, k4.w, acc.w);
  }
  red[sg][hq] = acc;
  __syncthreads();
  if (tid < 128) {
    int hq2 = tid >> 2, c = tid & 3;
    float s = 0.f;
    #pragma unroll
    for (int i = 0; i < 8; ++i) s += ((const float*)&red[i][hq2])[c];
    ctxT[(slab * 128 + hq2 * 4 + c) * 64 + b] = s;
  }
}

// gctxT[j][b] = b_ih[j] + ctx . W_ih[j, E:].  One block per j, 4-wave K-split.
__global__ void k_gctx(const float* __restrict__ ctxT, const float* __restrict__ Wih,
                       const float* __restrict__ bih, float* __restrict__ gctxT) {
  int j = blockIdx.x;
  int lane = threadIdx.x & 63, wv = threadIdx.x >> 6;
  const float* wp = Wih + (long)j * 1536 + Edim + wv * 256;
  const float* xp = ctxT + (wv * 256) * 64 + lane;
  float acc = 0.f;
  #pragma unroll 8
  for (int h = 0; h < 256; ++h) acc = fmaf(xp[h * 64], wp[h], acc);
  __shared__ float red[4][64];
  red[wv][lane] = acc;
  __syncthreads();
  if (threadIdx.x < 64)
    gctxT[(long)j * 64 + threadIdx.x] = red[0][threadIdx.x] + red[1][threadIdx.x] +
                                        red[2][threadIdx.x] + red[3][threadIdx.x] + bih[j];
}

// hT[k][b] = h0[b][k]; embT[e][b] = relu(emb_table[START=1][e])
__global__ void k_init(const float* __restrict__ h0, const float* __restrict__ embt,
                       float* __restrict__ hT, float* __restrict__ embT) {
  int idx = blockIdx.x * 256 + threadIdx.x;
  if (idx < Bdim * Hdim) {
    int b = idx >> 10, k = idx & 1023;
    hT[k * 64 + b] = h0[idx];
  } else {
    int j = idx - Bdim * Hdim;
    if (j < Edim * 64) {
      int e = j >> 6;
      float x = embt[1 * Edim + e];
      embT[j] = x > 0.f ? x : 0.f;
    }
  }
}

// W_out fp32 -> bf16 copy (one time)
__global__ void k_w2b(const float* __restrict__ W, unsigned short* __restrict__ Wb) {
  long i = ((long)blockIdx.x * 256 + threadIdx.x) * 8;
  float4 a = *(const float4*)(W + i);
  float4 b = *(const float4*)(W + i + 4);
  short8 v;
  v[0] = (short)f2bf(a.x); v[1] = (short)f2bf(a.y); v[2] = (short)f2bf(a.z); v[3] = (short)f2bf(a.w);
  v[4] = (short)f2bf(b.x); v[5] = (short)f2bf(b.y); v[6] = (short)f2bf(b.z); v[7] = (short)f2bf(b.w);
  *(short8*)(Wb + i) = v;
}

// ---------- per-step kernels ----------

// GRU step, fp32. 2 hid/block, weights staged in LDS (coalesced), LDS-broadcast compute.
// 512 blocks x 512 threads, 60 KB LDS -> 2 blocks/CU, VALU-bound core.
__launch_bounds__(512)
__global__ void k_gru(const float* __restrict__ hT_in, float* __restrict__ hT_out,
                      const float* __restrict__ embT, const float* __restrict__ gctxT,
                      const float* __restrict__ Wih, const float* __restrict__ Whh,
                      const float* __restrict__ bhh,
                      float* __restrict__ hrow, unsigned short* __restrict__ hb) {
  __shared__ float wE[6][Edim];      // 12 KB, row r = gate*2 + hi
  __shared__ float wH[6][Hdim];      // 24 KB
  __shared__ float red[8][12][64];   // 24 KB
  int tid = threadIdx.x, lane = tid & 63, wv = tid >> 6;  // wv 0..7
  int hid0 = blockIdx.x * 2;
  // stage weights (coalesced float4)
  for (int i = tid; i < 6 * 128; i += 512) {
    int r = i >> 7, c = (i & 127) << 2;
    int row = (r >> 1) * Hdim + hid0 + (r & 1);
    *(float4*)&wE[r][c] = *(const float4*)(Wih + (long)row * 1536 + c);
  }
  for (int i = tid; i < 6 * 256; i += 512) {
    int r = i >> 8, c = (i & 255) << 2;
    int row = (r >> 1) * Hdim + hid0 + (r & 1);
    *(float4*)&wH[r][c] = *(const float4*)(Whh + (long)row * Hdim + c);
  }
  __syncthreads();
  float aE[6] = {0, 0, 0, 0, 0, 0}, aH[6] = {0, 0, 0, 0, 0, 0};
  int e0 = wv * 64;
  #pragma unroll 2
  for (int e = e0; e < e0 + 64; e += 4) {
    float x0 = embT[(e + 0) * 64 + lane];
    float x1 = embT[(e + 1) * 64 + lane];
    float x2 = embT[(e + 2) * 64 + lane];
    float x3 = embT[(e + 3) * 64 + lane];
    #pragma unroll
    for (int r = 0; r < 6; ++r) {
      float4 w = *(const float4*)&wE[r][e];
      aE[r] = fmaf(w.x, x0, aE[r]); aE[r] = fmaf(w.y, x1, aE[r]);
      aE[r] = fmaf(w.z, x2, aE[r]); aE[r] = fmaf(w.w, x3, aE[r]);
    }
  }
  int k0 = wv * 128;
  #pragma unroll 2
  for (int k = k0; k < k0 + 128; k += 4) {
    float x0 = hT_in[(k + 0) * 64 + lane];
    float x1 = hT_in[(k + 1) * 64 + lane];
    float x2 = hT_in[(k + 2) * 64 + lane];
    float x3 = hT_in[(k + 3) * 64 + lane];
    #pragma unroll
    for (int r = 0; r < 6; ++r) {
      float4 w = *(const float4*)&wH[r][k];
      aH[r] = fmaf(w.x, x0, aH[r]); aH[r] = fmaf(w.y, x1, aH[r]);
      aH[r] = fmaf(w.z, x2, aH[r]); aH[r] = fmaf(w.w, x3, aH[r]);
    }
  }
  #pragma unroll
  for (int r = 0; r < 6; ++r) {
    red[wv][r][lane] = aE[r];
    red[wv][6 + r][lane] = aH[r];
  }
  __syncthreads();
  if (tid < 128) {
    int hi = tid >> 6, b = tid & 63, hid = hid0 + hi;
    float sE[3] = {0, 0, 0}, sH[3] = {0, 0, 0};
    #pragma unroll
    for (int w2 = 0; w2 < 8; ++w2) {
      #pragma unroll
      for (int q = 0; q < 3; ++q) {
        sE[q] += red[w2][q * 2 + hi][b];
        sH[q] += red[w2][6 + q * 2 + hi][b];
      }
    }
    float gr = gctxT[(long)(0 * Hdim + hid) * 64 + b] + sE[0];
    float gz = gctxT[(long)(1 * Hdim + hid) * 64 + b] + sE[1];
    float gn = gctxT[(long)(2 * Hdim + hid) * 64 + b] + sE[2];
    float hr = sH[0] + bhh[hid];
    float hz = sH[1] + bhh[Hdim + hid];
    float hn = sH[2] + bhh[2 * Hdim + hid];
    float r = 1.f / (1.f + expf(-(gr + hr)));
    float z = 1.f / (1.f + expf(-(gz + hz)));
    float n = tanhf(gn + r * hn);
    float hold = hT_in[hid * 64 + b];
    float hnew = (1.f - z) * n + z * hold;
    hT_out[hid * 64 + b] = hnew;
    hrow[b * Hdim + hid] = hnew;
    hb[b * Hdim + hid] = f2bf(hnew);
  }
}

template <int WB>
__device__ __forceinline__ short8 loadB(const unsigned short* Bq, const float* Bqf, int off) {
  if (WB) {
    return *(const short8*)(Bq + off);
  } else {
    float4 x = *(const float4*)(Bqf + off);
    float4 y = *(const float4*)(Bqf + off + 4);
    short8 v;
    v[0] = (short)f2bf(x.x); v[1] = (short)f2bf(x.y); v[2] = (short)f2bf(x.z); v[3] = (short)f2bf(x.w);
    v[4] = (short)f2bf(y.x); v[5] = (short)f2bf(y.y); v[6] = (short)f2bf(y.z); v[7] = (short)f2bf(y.w);
    return v;
  }
}

// logits[b,v] = h_bf16 . W_out_bf16 + b_out via MFMA 16x16x32 bf16.
// 250 blocks x 4 waves; each wave: 32 v-cols (2 n-tiles) x 64 b. B double-buffered.
template <int WB>
__launch_bounds__(256)
__global__ void k_logits(const unsigned short* __restrict__ hbv,
                         const unsigned short* __restrict__ Wb,
                         const float* __restrict__ Wf,
                         const float* __restrict__ bout, float* __restrict__ out,
                         int t, float* __restrict__ wsmax) {
  int tid = threadIdx.x, wv = tid >> 6, lane = tid & 63;
  int l15 = lane & 15, quad = lane >> 4;
  int n32 = (blockIdx.x * 4 + wv) * 32;
  int vcol0 = n32 + l15, vcol1 = n32 + 16 + l15;
  f32x4 acc[2][4];
  #pragma unroll
  for (int nt = 0; nt < 2; ++nt)
    #pragma unroll
    for (int mt = 0; mt < 4; ++mt) acc[nt][mt] = (f32x4){0.f, 0.f, 0.f, 0.f};
  const unsigned short* A = hbv + l15 * Hdim + quad * 8;
  const unsigned short* Bq0 = WB ? (Wb + (long)vcol0 * Hdim + quad * 8) : nullptr;
  const unsigned short* Bq1 = WB ? (Wb + (long)vcol1 * Hdim + quad * 8) : nullptr;
  const float* Bf0 = WB ? nullptr : (Wf + (long)vcol0 * Hdim + quad * 8);
  const float* Bf1 = WB ? nullptr : (Wf + (long)vcol1 * Hdim + quad * 8);
  short8 b0c = loadB<WB>(Bq0, Bf0, 0);
  short8 b1c = loadB<WB>(Bq1, Bf1, 0);
  #pragma unroll 4
  for (int ks = 0; ks < 32; ++ks) {
    int k0 = ks * 32;
    short8 b0n, b1n;
    if (ks < 31) {
      b0n = loadB<WB>(Bq0, Bf0, k0 + 32);
      b1n = loadB<WB>(Bq1, Bf1, k0 + 32);
    }
    short8 a0 = *(const short8*)(A + k0);
    short8 a1 = *(const short8*)(A + 16 * Hdim + k0);
    short8 a2 = *(const short8*)(A + 32 * Hdim + k0);
    short8 a3 = *(const short8*)(A + 48 * Hdim + k0);
    acc[0][0] = __builtin_amdgcn_mfma_f32_16x16x32_bf16(a0, b0c, acc[0][0], 0, 0, 0);
    acc[0][1] = __builtin_amdgcn_mfma_f32_16x16x32_bf16(a1, b0c, acc[0][1], 0, 0, 0);
    acc[0][2] = __builtin_amdgcn_mfma_f32_16x16x32_bf16(a2, b0c, acc[0][2], 0, 0, 0);
    acc[0][3] = __builtin_amdgcn_mfma_f32_16x16x32_bf16(a3, b0c, acc[0][3], 0, 0, 0);
    acc[1][0] = __builtin_amdgcn_mfma_f32_16x16x32_bf16(a0, b1c, acc[1][0], 0, 0, 0);
    acc[1][1] = __builtin_amdgcn_mfma_f32_16x16x32_bf16(a1, b1c, acc[1][1], 0, 0, 0);
    acc[1][2] = __builtin_amdgcn_mfma_f32_16x16x32_bf16(a2, b1c, acc[1][2], 0, 0, 0);
    acc[1][3] = __builtin_amdgcn_mfma_f32_16x16x32_bf16(a3, b1c, acc[1][3], 0, 0, 0);
    b0c = b0n; b1c = b1n;
  }
  __shared__ float lmax[4][64];
  float bo0 = bout[vcol0], bo1 = bout[vcol1];
  float* Ot = out + (long)t * Vdim;
  #pragma unroll
  for (int mt = 0; mt < 4; ++mt) {
    #pragma unroll
    for (int r = 0; r < 4; ++r) {
      int brow = mt * 16 + quad * 4 + r;  // C/D: row=quad*4+reg, col=l15 (m89-verified)
      float v0 = acc[0][mt][r] + bo0;
      float v1 = acc[1][mt][r] + bo1;
      Ot[(long)brow * TV + vcol0] = v0;
      Ot[(long)brow * TV + vcol1] = v1;
      float m = fmaxf(v0, v1);
      m = fmaxf(m, __shfl_xor(m, 1));
      m = fmaxf(m, __shfl_xor(m, 2));
      m = fmaxf(m, __shfl_xor(m, 4));
      m = fmaxf(m, __shfl_xor(m, 8));
      if (l15 == 0) lmax[wv][brow] = m;
    }
  }
  __syncthreads();
  if (tid < 64) {
    float m = fmaxf(fmaxf(lmax[0][tid], lmax[1][tid]), fmaxf(lmax[2][tid], lmax[3][tid]));
    wsmax[tid * 256 + blockIdx.x] = m;  // [b][block]; block covers 128 cols
  }
}

// greedy argmax: prune via per-block maxima, fp32-recheck near-max candidates,
// gather next embedding. One block per b.
__global__ void k_argmax(const float* __restrict__ wsmax, const float* __restrict__ out,
                         const float* __restrict__ hrow, const float* __restrict__ Wout,
                         const float* __restrict__ bout, const float* __restrict__ embt,
                         float* __restrict__ embT, int t) {
  int b = blockIdx.x, tid = threadIdx.x;  // 256 threads
  __shared__ float lred[4];
  __shared__ float thr_s;
  __shared__ int qn, cnt, tok_s;
  __shared__ int qblk[32];
  __shared__ int cand[64];
  __shared__ float cval[64];
  float mv = (tid < 250) ? wsmax[b * 256 + tid] : -1e30f;
  float m = mv;
  for (int off = 32; off; off >>= 1) m = fmaxf(m, __shfl_down(m, off));
  if ((tid & 63) == 0) lred[tid >> 6] = m;
  if (tid == 0) { qn = 0; cnt = 0; }
  __syncthreads();
  if (tid == 0)
    thr_s = fmaxf(fmaxf(lred[0], lred[1]), fmaxf(lred[2], lred[3])) - 0.03f;
  __syncthreads();
  float thr = thr_s;
  if (mv >= thr) {
    int i = atomicAdd(&qn, 1);
    if (i < 32) qblk[i] = tid;
  }
  __syncthreads();
  int QN = min(qn, 32);
  const float* L = out + (long)b * TV + (long)t * Vdim;
  for (int j = tid; j < QN * 128; j += 256) {
    int blk = qblk[j >> 7];
    int v = blk * 128 + (j & 127);
    float val = L[v];
    if (val >= thr) {
      int i = atomicAdd(&cnt, 1);
      if (i < 64) cand[i] = v;
    }
  }
  __syncthreads();
  int C = min(cnt, 64);
  int tok;
  if (C == 1) {
    tok = cand[0];  // margin 0.03 > 2*bf16 error -> no recheck needed
  } else {
    for (int c = 0; c < C; ++c) {
      int v = cand[c];
      const float* wr = Wout + (long)v * Hdim;
      const float* hr = hrow + b * Hdim;
      float p = 0.f;
      for (int k = tid; k < Hdim; k += 256) p = fmaf(hr[k], wr[k], p);
      for (int off = 32; off; off >>= 1) p += __shfl_down(p, off);
      __syncthreads();
      if ((tid & 63) == 0) lred[tid >> 6] = p;
      __syncthreads();
      if (tid == 0) cval[c] = lred[0] + lred[1] + lred[2] + lred[3] + bout[v];
    }
    __syncthreads();
    if (tid == 0) {
      float best = -1e30f;
      int bi = 0x7fffffff;
      for (int c = 0; c < C; ++c)
        if (cval[c] > best || (cval[c] == best && cand[c] < bi)) { best = cval[c]; bi = cand[c]; }
      tok_s = bi;
    }
    __syncthreads();
    tok = tok_s;
  }
  for (int e = tid; e < Edim; e += 256) {
    float x = embt[(long)tok * Edim + e];
    embT[e * 64 + b] = x > 0.f ? x : 0.f;
  }
}

// ---------- host ----------

extern "C" void kernel_launch(void* const* d_in, const int* in_sizes, int n_in,
                              void* d_out, int out_size, void* d_ws, size_t ws_size,
                              hipStream_t stream) {
  const float* keys = (const float*)d_in[0];
  const float* h0   = (const float*)d_in[1];
  const float* embt = (const float*)d_in[2];
  const float* Ua   = (const float*)d_in[4];
  const float* Va   = (const float*)d_in[5];
  const float* Wih  = (const float*)d_in[6];
  const float* Whh  = (const float*)d_in[7];
  const float* bih  = (const float*)d_in[8];
  const float* bhh  = (const float*)d_in[9];
  const float* Wout = (const float*)d_in[10];
  const float* bout = (const float*)d_in[11];
  float* out = (float*)d_out;

  char* ws = (char*)d_ws;
  float* u     = (float*)(ws + 0);          // 4 KB
  float* pu    = (float*)(ws + 4096);       // 32 KB
  float* sc    = (float*)(ws + 36864);      // 24 KB
  float* wbuf  = (float*)(ws + 61440);      // 24 KB
  float* ctxT  = (float*)(ws + 86016);      // 256 KB
  float* gctxT = (float*)(ws + 348160);     // 768 KB
  float* hTa   = (float*)(ws + 1134592);    // 256 KB
  float* hTb   = (float*)(ws + 1396736);    // 256 KB
  float* embT  = (float*)(ws + 1658880);    // 128 KB
  float* wsmax = (float*)(ws + 1789952);    // 64 KB
  unsigned short* hb = (unsigned short*)(ws + 1855488);  // 128 KB
  unsigned short* Wb = (unsigned short*)(ws + 1986560);  // 64 MB
  bool useBf = ws_size >= 67522560ull;

  float* houtrow = out + O1;  // h_T slot, overwritten each step (last wins)
  float* attn = out + O2;

  k_u1<<<128, 256, 0, stream>>>(Va, Ua, pu);
  k_u2<<<4, 256, 0, stream>>>(pu, u);
  k_sc<<<1536, 256, 0, stream>>>(keys, u, sc);
  k_softmax<<<64, 128, 0, stream>>>(sc, wbuf, attn);
  k_ctx<<<512, 256, 0, stream>>>(wbuf, keys, ctxT);
  k_gctx<<<3072, 256, 0, stream>>>(ctxT, Wih, bih, gctxT);
  k_init<<<384, 256, 0, stream>>>(h0, embt, hTa, embT);
  if (useBf) k_w2b<<<16000, 256, 0, stream>>>(Wout, Wb);

  float* hin = hTa;
  float* hout = hTb;
  for (int t = 0; t < Tdim; ++t) {
    k_gru<<<512, 512, 0, stream>>>(hin, hout, embT, gctxT, Wih, Whh, bhh, houtrow, hb);
    if (useBf)
      k_logits<1><<<250, 256, 0, stream>>>(hb, Wb, nullptr, bout, out, t, wsmax);
    else
      k_logits<0><<<250, 256, 0, stream>>>(hb, nullptr, Wout, bout, out, t, wsmax);
    if (t < Tdim - 1)
      k_argmax<<<64, 256, 0, stream>>>(wsmax, out, houtrow, Wout, bout, embt, embT, t);
    float* tmp = hin; hin = hout; hout = tmp;
  }
}